// Round 7
// baseline (493.516 us; speedup 1.0000x reference)
//
#include <hip/hip_runtime.h>
#include <math.h>

#define HD 56
#define WD 56
#define CD 64
#define PLANE 3136   // 56*56

typedef _Float16 f16x8 __attribute__((ext_vector_type(8)));
typedef float    f32x4 __attribute__((ext_vector_type(4)));

// ---- weight transpose + f16: wT[k][o][c] = (f16)w[o][c][k] ----
__global__ __launch_bounds__(256) void wtrans_k(
    const float* __restrict__ w1, const float* __restrict__ w3, const float* __restrict__ w2,
    _Float16* __restrict__ t1, _Float16* __restrict__ t3, _Float16* __restrict__ t2)
{
    const float* src; _Float16* dst; int K2;
    if (blockIdx.y == 0)      { src = w1; dst = t1; K2 = 9;  }
    else if (blockIdx.y == 1) { src = w3; dst = t3; K2 = 25; }
    else                      { src = w2; dst = t2; K2 = 9;  }
    int total = 64 * 64 * K2;
    for (int idx = blockIdx.x * 256 + threadIdx.x; idx < total; idx += gridDim.x * 256) {
        int k = idx >> 12;
        int o = (idx >> 6) & 63;
        int c = idx & 63;
        dst[idx] = (_Float16)src[(o * 64 + c) * K2 + k];
    }
}

// ---------------- 3x3 offset conv (fp32), pad 1, stride 1 ----------------
template<int COT>
__global__ __launch_bounds__(256) void offconv_k(
    const float* __restrict__ src, const float* __restrict__ w,
    const float* __restrict__ bias, float* __restrict__ dst, int Co, int NG)
{
    __shared__ float wl[COT * 768];
    int tid = threadIdx.x;
    int bid = blockIdx.x;
    int b   = bid & 7;
    int r   = bid >> 3;
    int co0 = (r % NG) * COT;
    int pixblk = r / NG;

    for (int idx = tid; idx < COT * 768; idx += 256) wl[idx] = 0.f;
    __syncthreads();
    for (int idx = tid; idx < COT * 576; idx += 256) {
        int i   = idx / 576;
        int rem = idx - i * 576;
        int c   = rem / 9;
        int kk  = rem - c * 9;
        wl[i * 768 + c * 12 + kk] = w[(co0 + i) * 576 + rem];
    }
    __syncthreads();

    int pix = pixblk * 256 + tid;
    if (pix >= PLANE) return;
    int ho = pix / WD, wo = pix - ho * WD;

    float acc[COT];
#pragma unroll
    for (int i = 0; i < COT; ++i) acc[i] = bias[co0 + i];

    const float* sb = src + b * (CD * PLANE);
    for (int c = 0; c < CD; ++c) {
        const float* sc = sb + c * PLANE;
        float v[12];
#pragma unroll
        for (int ky = 0; ky < 3; ++ky) {
            int y = ho + ky - 1;
            bool yv = (unsigned)y < (unsigned)HD;
#pragma unroll
            for (int kx = 0; kx < 3; ++kx) {
                int xx = wo + kx - 1;
                v[ky * 3 + kx] = (yv && (unsigned)xx < (unsigned)WD) ? sc[y * WD + xx] : 0.f;
            }
        }
        v[9] = v[10] = v[11] = 0.f;
#pragma unroll
        for (int i = 0; i < COT; ++i) {
            const float* wr = &wl[i * 768 + c * 12];
#pragma unroll
            for (int kk = 0; kk < 12; ++kk) acc[i] += wr[kk] * v[kk];
        }
    }
    float* db = dst + (size_t)(b * Co + co0) * PLANE + pix;
#pragma unroll
    for (int i = 0; i < COT; ++i) db[i * PLANE] = acc[i];
}

// ---------------- deformable conv + BN: LDS-free, barrier-free, per-wave ----------------
// MERGED==1: out = relu(bnA(dcA)) + relu(bnB(dcB))    (3x3 pad2 dil2 + 5x5 pad4 dil2)
// MERGED==0: out = relu(bnA(dcA) + addsrc)
// grid: 392 blocks x 256 thr = 1568 independent waves; batch = bid&7 (XCD-local).
// Wave = 16 row-major-contiguous pixels (196 tiles x 16 = 3136 exact) x 64 out-chans.
// Lane (n=l&15, g=l>>4): gathers channels 8g+j (khalf0) / 32+8g+j (khalf1) for pixel n
// -> gathered vector IS the mfma_16x16x32 B-fragment. A-frags per-lane from L2-hot wT.
// Software pipeline: gathers+A(t+1) and dydx(t+2) in flight during MFMA(t). No LDS.

#define LOAD_DYDX(TAP, DY, DX)                                                \
  { int kph_; const float* offs_;                                             \
    if (!MERGED || (TAP) < 9) { kph_ = (TAP); offs_ = offsAb; }               \
    else { kph_ = (TAP) - 9; offs_ = offsBb; }                                \
    DY = offs_[(2 * kph_) * PLANE + pix];                                     \
    DX = offs_[(2 * kph_ + 1) * PLANE + pix]; }

#define PREP_TAP(TAP, dyv, dxv, AFDST, WN)                                    \
  {                                                                           \
    int kph_, byy_, bxx_; const _Float16* wk_;                                \
    if (!MERGED || (TAP) < 9) {                                               \
      kph_ = (TAP); wk_ = wTA + kph_ * 4096;                                  \
      byy_ = (kph_ / 3) * 2 - 2; bxx_ = (kph_ % 3) * 2 - 2;                   \
    } else {                                                                  \
      kph_ = (TAP) - 9; wk_ = wTB + kph_ * 4096;                              \
      byy_ = (kph_ / 5) * 2 - 4; bxx_ = (kph_ % 5) * 2 - 4;                   \
    }                                                                         \
    float py_ = (dyv) + (float)(byy_ + ho);                                   \
    float px_ = (dxv) + (float)(bxx_ + wo);                                   \
    float fy_ = floorf(py_), fx_ = floorf(px_);                               \
    float wy1_ = py_ - fy_, wx1_ = px_ - fx_;                                 \
    float wy0_ = 1.f - wy1_, wx0_ = 1.f - wx1_;                               \
    int y0_ = (int)fy_, x0_ = (int)fx_;                                       \
    int y1_ = y0_ + 1, x1_ = x0_ + 1;                                         \
    float vy0_ = (y0_ >= 0 && y0_ < HD) ? 1.f : 0.f;                          \
    float vy1_ = (y1_ >= 0 && y1_ < HD) ? 1.f : 0.f;                          \
    float vx0_ = (x0_ >= 0 && x0_ < WD) ? 1.f : 0.f;                          \
    float vx1_ = (x1_ >= 0 && x1_ < WD) ? 1.f : 0.f;                          \
    int cy0_ = min(max(y0_, 0), HD - 1), cy1_ = min(max(y1_, 0), HD - 1);     \
    int cx0_ = min(max(x0_, 0), WD - 1), cx1_ = min(max(x1_, 0), WD - 1);     \
    int i00_ = cy0_ * WD + cx0_, i01_ = cy0_ * WD + cx1_;                     \
    int i10_ = cy1_ * WD + cx0_, i11_ = cy1_ * WD + cx1_;                     \
    WN = make_float4(wy0_ * wx0_ * vy0_ * vx0_, wy0_ * wx1_ * vy0_ * vx1_,    \
                     wy1_ * wx0_ * vy1_ * vx0_, wy1_ * wx1_ * vy1_ * vx1_);   \
    _Pragma("unroll")                                                         \
    for (int j = 0; j < 8; ++j) {                                             \
      qa0[j] = gp0[j * PLANE + i00_]; qa1[j] = gp0[j * PLANE + i01_];         \
      qa2[j] = gp0[j * PLANE + i10_]; qa3[j] = gp0[j * PLANE + i11_];         \
      qb0[j] = gp1[j * PLANE + i00_]; qb1[j] = gp1[j * PLANE + i01_];         \
      qb2[j] = gp1[j * PLANE + i10_]; qb3[j] = gp1[j * PLANE + i11_];         \
    }                                                                         \
    _Pragma("unroll")                                                         \
    for (int ot = 0; ot < 4; ++ot) {                                          \
      int oo_ = ot * 16 + n;                                                  \
      AFDST[ot][0] = *(const f16x8*)&wk_[oo_ * 64 + g * 8];                   \
      AFDST[ot][1] = *(const f16x8*)&wk_[oo_ * 64 + 32 + g * 8];              \
    }                                                                         \
  }

template<int MERGED>
__global__ __launch_bounds__(256) void dconv_k(
    const float* __restrict__ x,
    const float* __restrict__ offsA, const float* __restrict__ offsB,
    const _Float16* __restrict__ wTA, const _Float16* __restrict__ wTB, // [k][o][c]
    const float* __restrict__ gA, const float* __restrict__ bA,
    const float* __restrict__ mA, const float* __restrict__ vA,
    const float* __restrict__ gB, const float* __restrict__ bB,
    const float* __restrict__ mB, const float* __restrict__ vB,
    const float* __restrict__ addsrc, float* __restrict__ out)
{
    constexpr int NT = MERGED ? 34 : 9;
    int tid = threadIdx.x;
    int bid = blockIdx.x;
    int b   = bid & 7;
    int l   = tid & 63;
    int n   = l & 15;
    int g   = l >> 4;
    int tile = (bid >> 3) * 4 + (tid >> 6);
    int pix = tile * 16 + n;
    int ho  = pix / WD;
    int wo  = pix - ho * WD;

    const float* xb  = x + b * (CD * PLANE);
    const float* gp0 = xb + (g * 8) * PLANE;
    const float* gp1 = xb + (32 + g * 8) * PLANE;
    const float* offsAb = offsA + b * (18 * PLANE);
    const float* offsBb = MERGED ? (offsB + b * (50 * PLANE)) : offsA;

    f32x4 accA[4], accB[4];
#pragma unroll
    for (int ot = 0; ot < 4; ++ot) {
        accA[ot] = (f32x4){0.f, 0.f, 0.f, 0.f};
        accB[ot] = (f32x4){0.f, 0.f, 0.f, 0.f};
    }

    float qa0[8], qa1[8], qa2[8], qa3[8];
    float qb0[8], qb1[8], qb2[8], qb3[8];
    f16x8 af[4][2], afn[4][2];
    float4 wcur, wnxt;
    float dyn, dxn;

    // prologue: prep tap 0, preload dydx for tap 1
    {
        float dy0, dx0;
        LOAD_DYDX(0, dy0, dx0);
        PREP_TAP(0, dy0, dx0, af, wcur);
    }
    LOAD_DYDX(1, dyn, dxn);

#pragma unroll 1
    for (int tap = 0; tap < NT; ++tap) {
        // B-fragments for current tap (waits on gathers issued last iter)
        f16x8 b0, b1;
#pragma unroll
        for (int j = 0; j < 8; ++j) {
            b0[j] = (_Float16)(wcur.x * qa0[j] + wcur.y * qa1[j] + wcur.z * qa2[j] + wcur.w * qa3[j]);
            b1[j] = (_Float16)(wcur.x * qb0[j] + wcur.y * qb1[j] + wcur.z * qb2[j] + wcur.w * qb3[j]);
        }
        bool hn = (tap + 1 < NT);
        if (hn) {
            PREP_TAP(tap + 1, dyn, dxn, afn, wnxt);        // issue next gathers + A-frags
            int t3 = (tap + 2 < NT) ? (tap + 2) : (NT - 1);
            LOAD_DYDX(t3, dyn, dxn);                       // dydx two taps ahead
        }
        if (!MERGED || tap < 9) {
#pragma unroll
            for (int ot = 0; ot < 4; ++ot) {
                accA[ot] = __builtin_amdgcn_mfma_f32_16x16x32_f16(af[ot][0], b0, accA[ot], 0, 0, 0);
                accA[ot] = __builtin_amdgcn_mfma_f32_16x16x32_f16(af[ot][1], b1, accA[ot], 0, 0, 0);
            }
        } else {
#pragma unroll
            for (int ot = 0; ot < 4; ++ot) {
                accB[ot] = __builtin_amdgcn_mfma_f32_16x16x32_f16(af[ot][0], b0, accB[ot], 0, 0, 0);
                accB[ot] = __builtin_amdgcn_mfma_f32_16x16x32_f16(af[ot][1], b1, accB[ot], 0, 0, 0);
            }
        }
        if (hn) {
#pragma unroll
            for (int ot = 0; ot < 4; ++ot) { af[ot][0] = afn[ot][0]; af[ot][1] = afn[ot][1]; }
            wcur = wnxt;
        }
    }

    // epilogue: D layout: col(pixel) = l&15 = n, row(o within 16-tile) = g*4 + rr
#pragma unroll
    for (int ot = 0; ot < 4; ++ot) {
#pragma unroll
        for (int rr = 0; rr < 4; ++rr) {
            int o = ot * 16 + g * 4 + rr;
            float ivA = gA[o] * (1.f / sqrtf(vA[o] + 1e-5f));
            float shA = bA[o] - mA[o] * ivA;
            size_t oidx = (size_t)(b * 64 + o) * PLANE + pix;
            float vA_ = accA[ot][rr] * ivA + shA;
            if (MERGED) {
                float ivB = gB[o] * (1.f / sqrtf(vB[o] + 1e-5f));
                float shB = bB[o] - mB[o] * ivB;
                float vB_ = accB[ot][rr] * ivB + shB;
                out[oidx] = fmaxf(vA_, 0.f) + fmaxf(vB_, 0.f);
            } else {
                out[oidx] = fmaxf(vA_ + addsrc[oidx], 0.f);
            }
        }
    }
}

extern "C" void kernel_launch(void* const* d_in, const int* in_sizes, int n_in,
                              void* d_out, int out_size, void* d_ws, size_t ws_size,
                              hipStream_t stream) {
    const float* x   = (const float*)d_in[0];
    const float* ow1 = (const float*)d_in[1];
    const float* ob1 = (const float*)d_in[2];
    const float* ow3 = (const float*)d_in[3];
    const float* ob3 = (const float*)d_in[4];
    const float* ow2 = (const float*)d_in[5];
    const float* ob2 = (const float*)d_in[6];
    const float* w1  = (const float*)d_in[7];
    const float* w3  = (const float*)d_in[8];
    const float* w2  = (const float*)d_in[9];
    const float* g1  = (const float*)d_in[10];
    const float* b1  = (const float*)d_in[11];
    const float* m1  = (const float*)d_in[12];
    const float* v1  = (const float*)d_in[13];
    const float* g3  = (const float*)d_in[14];
    const float* b3  = (const float*)d_in[15];
    const float* m3  = (const float*)d_in[16];
    const float* v3  = (const float*)d_in[17];
    const float* g2  = (const float*)d_in[18];
    const float* b2  = (const float*)d_in[19];
    const float* m2  = (const float*)d_in[20];
    const float* v2  = (const float*)d_in[21];

    float* out = (float*)d_out;
    float* ws  = (float*)d_ws;

    float* offs1 = ws;                    // 8*18*3136 floats (reused for offs2)
    float* offs3 = ws + 451584;           // 8*50*3136
    float* mid   = ws + 1705984;          // 8*64*3136
    float* fbase = ws + 3311616;
    _Float16* wT1h = (_Float16*)fbase;                    // 36864 f16
    _Float16* wT3h = (_Float16*)(fbase + 18432);          // 102400 f16
    _Float16* wT2h = (_Float16*)(fbase + 18432 + 51200);  // 36864 f16

    wtrans_k<<<dim3(16, 3), dim3(256), 0, stream>>>(w1, w3, w2, wT1h, wT3h, wT2h);

    offconv_k<6><<<dim3(13 * 3 * 8),  dim3(256), 0, stream>>>(x, ow1, ob1, offs1, 18, 3);
    offconv_k<10><<<dim3(13 * 5 * 8), dim3(256), 0, stream>>>(x, ow3, ob3, offs3, 50, 5);

    dconv_k<1><<<dim3(392), dim3(256), 0, stream>>>(
        x, offs1, offs3, wT1h, wT3h, g1, b1, m1, v1, g3, b3, m3, v3, nullptr, mid);

    offconv_k<6><<<dim3(13 * 3 * 8), dim3(256), 0, stream>>>(mid, ow2, ob2, offs1, 18, 3);

    dconv_k<0><<<dim3(392), dim3(256), 0, stream>>>(
        mid, offs1, nullptr, wT2h, nullptr, g2, b2, m2, v2,
        nullptr, nullptr, nullptr, nullptr, x, out);
}

// Round 8
// 436.856 us; speedup vs baseline: 1.1297x; 1.1297x over previous
//
#include <hip/hip_runtime.h>
#include <math.h>

#define HD 56
#define WD 56
#define CD 64
#define PLANE 3136   // 56*56

typedef _Float16 f16x8 __attribute__((ext_vector_type(8)));
typedef float    f32x4 __attribute__((ext_vector_type(4)));

// ---- weight transpose + f16: wT[k][o][c] = (f16)w[o][c][k] ----
__global__ __launch_bounds__(256) void wtrans_k(
    const float* __restrict__ w1, const float* __restrict__ w3, const float* __restrict__ w2,
    _Float16* __restrict__ t1, _Float16* __restrict__ t3, _Float16* __restrict__ t2)
{
    const float* src; _Float16* dst; int K2;
    if (blockIdx.y == 0)      { src = w1; dst = t1; K2 = 9;  }
    else if (blockIdx.y == 1) { src = w3; dst = t3; K2 = 25; }
    else                      { src = w2; dst = t2; K2 = 9;  }
    int total = 64 * 64 * K2;
    for (int idx = blockIdx.x * 256 + threadIdx.x; idx < total; idx += gridDim.x * 256) {
        int k = idx >> 12;
        int o = (idx >> 6) & 63;
        int c = idx & 63;
        dst[idx] = (_Float16)src[(o * 64 + c) * K2 + k];
    }
}

// ---------------- 3x3 offset conv (fp32), pad 1, stride 1 ----------------
template<int COT>
__global__ __launch_bounds__(256) void offconv_k(
    const float* __restrict__ src, const float* __restrict__ w,
    const float* __restrict__ bias, float* __restrict__ dst, int Co, int NG)
{
    __shared__ float wl[COT * 768];
    int tid = threadIdx.x;
    int bid = blockIdx.x;
    int b   = bid & 7;
    int r   = bid >> 3;
    int co0 = (r % NG) * COT;
    int pixblk = r / NG;

    for (int idx = tid; idx < COT * 768; idx += 256) wl[idx] = 0.f;
    __syncthreads();
    for (int idx = tid; idx < COT * 576; idx += 256) {
        int i   = idx / 576;
        int rem = idx - i * 576;
        int c   = rem / 9;
        int kk  = rem - c * 9;
        wl[i * 768 + c * 12 + kk] = w[(co0 + i) * 576 + rem];
    }
    __syncthreads();

    int pix = pixblk * 256 + tid;
    if (pix >= PLANE) return;
    int ho = pix / WD, wo = pix - ho * WD;

    float acc[COT];
#pragma unroll
    for (int i = 0; i < COT; ++i) acc[i] = bias[co0 + i];

    const float* sb = src + b * (CD * PLANE);
    for (int c = 0; c < CD; ++c) {
        const float* sc = sb + c * PLANE;
        float v[12];
#pragma unroll
        for (int ky = 0; ky < 3; ++ky) {
            int y = ho + ky - 1;
            bool yv = (unsigned)y < (unsigned)HD;
#pragma unroll
            for (int kx = 0; kx < 3; ++kx) {
                int xx = wo + kx - 1;
                v[ky * 3 + kx] = (yv && (unsigned)xx < (unsigned)WD) ? sc[y * WD + xx] : 0.f;
            }
        }
        v[9] = v[10] = v[11] = 0.f;
#pragma unroll
        for (int i = 0; i < COT; ++i) {
            const float* wr = &wl[i * 768 + c * 12];
#pragma unroll
            for (int kk = 0; kk < 12; ++kk) acc[i] += wr[kk] * v[kk];
        }
    }
    float* db = dst + (size_t)(b * Co + co0) * PLANE + pix;
#pragma unroll
    for (int i = 0; i < COT; ++i) db[i * PLANE] = acc[i];
}

// ---------------- deformable conv + BN: reg-direct, K-split across wave pairs ----------------
// MERGED==1: out = relu(bnA(dcA)) + relu(bnB(dcB))    (3x3 pad2 dil2 + 5x5 pad4 dil2)
// MERGED==0: out = relu(bnA(dcA) + addsrc)
// grid: 784 blocks x 256 thr = 3136 waves (12.25 waves/CU); batch = bid&7 (XCD-local).
// Block = 4 waves = 2 tiles x 2 K-halves. Wave (tile pr, khalf kh):
//   16 row-contiguous pixels x 64 out-chans, channels [kh*32, kh*32+32).
//   Lane (n=l&15, g=l>>4) gathers channels kh*32+8g+j for pixel n -> B-fragment direct.
//   4 MFMAs/tap (one per 16-o tile). A-frags per-lane from L2-hot wT. No LDS in tap loop.
// Final: kh=1 wave's partials added to kh=0's via LDS (idx-major, conflict-free), 1 barrier.

#define LOAD_DYDX(TAP, DY, DX)                                                \
  { int kph_; const float* offs_;                                             \
    if (!MERGED || (TAP) < 9) { kph_ = (TAP); offs_ = offsAb; }               \
    else { kph_ = (TAP) - 9; offs_ = offsBb; }                                \
    DY = offs_[(2 * kph_) * PLANE + pix];                                     \
    DX = offs_[(2 * kph_ + 1) * PLANE + pix]; }

#define PREP_TAP(TAP, dyv, dxv, AFDST, WN)                                    \
  {                                                                           \
    int kph_, byy_, bxx_; const _Float16* wk_;                                \
    if (!MERGED || (TAP) < 9) {                                               \
      kph_ = (TAP); wk_ = wTA + kph_ * 4096;                                  \
      byy_ = (kph_ / 3) * 2 - 2; bxx_ = (kph_ % 3) * 2 - 2;                   \
    } else {                                                                  \
      kph_ = (TAP) - 9; wk_ = wTB + kph_ * 4096;                              \
      byy_ = (kph_ / 5) * 2 - 4; bxx_ = (kph_ % 5) * 2 - 4;                   \
    }                                                                         \
    float py_ = (dyv) + (float)(byy_ + ho);                                   \
    float px_ = (dxv) + (float)(bxx_ + wo);                                   \
    float fy_ = floorf(py_), fx_ = floorf(px_);                               \
    float wy1_ = py_ - fy_, wx1_ = px_ - fx_;                                 \
    float wy0_ = 1.f - wy1_, wx0_ = 1.f - wx1_;                               \
    int y0_ = (int)fy_, x0_ = (int)fx_;                                       \
    int y1_ = y0_ + 1, x1_ = x0_ + 1;                                         \
    float vy0_ = (y0_ >= 0 && y0_ < HD) ? 1.f : 0.f;                          \
    float vy1_ = (y1_ >= 0 && y1_ < HD) ? 1.f : 0.f;                          \
    float vx0_ = (x0_ >= 0 && x0_ < WD) ? 1.f : 0.f;                          \
    float vx1_ = (x1_ >= 0 && x1_ < WD) ? 1.f : 0.f;                          \
    int cy0_ = min(max(y0_, 0), HD - 1), cy1_ = min(max(y1_, 0), HD - 1);     \
    int cx0_ = min(max(x0_, 0), WD - 1), cx1_ = min(max(x1_, 0), WD - 1);     \
    int i00_ = cy0_ * WD + cx0_, i01_ = cy0_ * WD + cx1_;                     \
    int i10_ = cy1_ * WD + cx0_, i11_ = cy1_ * WD + cx1_;                     \
    WN = make_float4(wy0_ * wx0_ * vy0_ * vx0_, wy0_ * wx1_ * vy0_ * vx1_,    \
                     wy1_ * wx0_ * vy1_ * vx0_, wy1_ * wx1_ * vy1_ * vx1_);   \
    _Pragma("unroll")                                                         \
    for (int j = 0; j < 8; ++j) {                                             \
      qa0[j] = gp[j * PLANE + i00_]; qa1[j] = gp[j * PLANE + i01_];           \
      qa2[j] = gp[j * PLANE + i10_]; qa3[j] = gp[j * PLANE + i11_];           \
    }                                                                         \
    _Pragma("unroll")                                                         \
    for (int ot = 0; ot < 4; ++ot)                                            \
      AFDST[ot] = *(const f16x8*)&wk_[(ot * 16 + n) * 64 + ckoff];            \
  }

template<int MERGED>
__global__ __launch_bounds__(256) void dconv_k(
    const float* __restrict__ x,
    const float* __restrict__ offsA, const float* __restrict__ offsB,
    const _Float16* __restrict__ wTA, const _Float16* __restrict__ wTB, // [k][o][c]
    const float* __restrict__ gA, const float* __restrict__ bA,
    const float* __restrict__ mA, const float* __restrict__ vA,
    const float* __restrict__ gB, const float* __restrict__ bB,
    const float* __restrict__ mB, const float* __restrict__ vB,
    const float* __restrict__ addsrc, float* __restrict__ out)
{
    constexpr int NT = MERGED ? 34 : 9;
    constexpr int RS = MERGED ? 32 : 16;            // reduce floats per lane
    __shared__ float red[2][RS * 64];               // [pair][idx*64 + lane]

    int tid = threadIdx.x;
    int bid = blockIdx.x;
    int b   = bid & 7;
    int l   = tid & 63;
    int n   = l & 15;
    int g   = l >> 4;
    int w   = tid >> 6;
    int kh  = w & 1;          // K-half
    int pr  = w >> 1;         // tile within block
    int tile = (bid >> 3) * 2 + pr;
    int pix = tile * 16 + n;
    int ho  = pix / WD;
    int wo  = pix - ho * WD;
    int ckoff = kh * 32 + g * 8;   // this lane's channel slice start

    const float* xb = x + b * (CD * PLANE);
    const float* gp = xb + ckoff * PLANE;           // gather base (8 channels)
    const float* offsAb = offsA + b * (18 * PLANE);
    const float* offsBb = MERGED ? (offsB + b * (50 * PLANE)) : offsA;

    f32x4 accA[4], accB[4];
#pragma unroll
    for (int ot = 0; ot < 4; ++ot) {
        accA[ot] = (f32x4){0.f, 0.f, 0.f, 0.f};
        accB[ot] = (f32x4){0.f, 0.f, 0.f, 0.f};
    }

    float qa0[8], qa1[8], qa2[8], qa3[8];
    f16x8 af[4], afn[4];
    float4 wcur, wnxt;
    float dyn, dxn;

    // prologue: prep tap 0, preload dydx for tap 1
    {
        float dy0, dx0;
        LOAD_DYDX(0, dy0, dx0);
        PREP_TAP(0, dy0, dx0, af, wcur);
    }
    LOAD_DYDX(1, dyn, dxn);

#pragma unroll 1
    for (int tap = 0; tap < NT; ++tap) {
        // B-fragment for current tap (waits on gathers issued last iter)
        f16x8 bf;
#pragma unroll
        for (int j = 0; j < 8; ++j)
            bf[j] = (_Float16)(wcur.x * qa0[j] + wcur.y * qa1[j] + wcur.z * qa2[j] + wcur.w * qa3[j]);
        bool hn = (tap + 1 < NT);
        if (hn) {
            PREP_TAP(tap + 1, dyn, dxn, afn, wnxt);        // issue next gathers + A-frags
            int t3 = (tap + 2 < NT) ? (tap + 2) : (NT - 1);
            LOAD_DYDX(t3, dyn, dxn);                       // dydx two taps ahead
        }
        if (!MERGED || tap < 9) {
#pragma unroll
            for (int ot = 0; ot < 4; ++ot)
                accA[ot] = __builtin_amdgcn_mfma_f32_16x16x32_f16(af[ot], bf, accA[ot], 0, 0, 0);
        } else {
#pragma unroll
            for (int ot = 0; ot < 4; ++ot)
                accB[ot] = __builtin_amdgcn_mfma_f32_16x16x32_f16(af[ot], bf, accB[ot], 0, 0, 0);
        }
        if (hn) {
#pragma unroll
            for (int ot = 0; ot < 4; ++ot) af[ot] = afn[ot];
            wcur = wnxt;
        }
    }

    // K-half reduce: kh=1 writes partials, kh=0 adds + epilogue
    if (kh == 1) {
#pragma unroll
        for (int ot = 0; ot < 4; ++ot)
#pragma unroll
            for (int rr = 0; rr < 4; ++rr) {
                red[pr][(ot * 4 + rr) * 64 + l] = accA[ot][rr];
                if (MERGED) red[pr][(16 + ot * 4 + rr) * 64 + l] = accB[ot][rr];
            }
    }
    __syncthreads();
    if (kh == 0) {
#pragma unroll
        for (int ot = 0; ot < 4; ++ot) {
#pragma unroll
            for (int rr = 0; rr < 4; ++rr) {
                int o = ot * 16 + g * 4 + rr;
                float aA = accA[ot][rr] + red[pr][(ot * 4 + rr) * 64 + l];
                float ivA = gA[o] * (1.f / sqrtf(vA[o] + 1e-5f));
                float shA = bA[o] - mA[o] * ivA;
                size_t oidx = (size_t)(b * 64 + o) * PLANE + pix;
                float vA_ = aA * ivA + shA;
                if (MERGED) {
                    float aB = accB[ot][rr] + red[pr][(16 + ot * 4 + rr) * 64 + l];
                    float ivB = gB[o] * (1.f / sqrtf(vB[o] + 1e-5f));
                    float shB = bB[o] - mB[o] * ivB;
                    float vB_ = aB * ivB + shB;
                    out[oidx] = fmaxf(vA_, 0.f) + fmaxf(vB_, 0.f);
                } else {
                    out[oidx] = fmaxf(vA_ + addsrc[oidx], 0.f);
                }
            }
        }
    }
}

extern "C" void kernel_launch(void* const* d_in, const int* in_sizes, int n_in,
                              void* d_out, int out_size, void* d_ws, size_t ws_size,
                              hipStream_t stream) {
    const float* x   = (const float*)d_in[0];
    const float* ow1 = (const float*)d_in[1];
    const float* ob1 = (const float*)d_in[2];
    const float* ow3 = (const float*)d_in[3];
    const float* ob3 = (const float*)d_in[4];
    const float* ow2 = (const float*)d_in[5];
    const float* ob2 = (const float*)d_in[6];
    const float* w1  = (const float*)d_in[7];
    const float* w3  = (const float*)d_in[8];
    const float* w2  = (const float*)d_in[9];
    const float* g1  = (const float*)d_in[10];
    const float* b1  = (const float*)d_in[11];
    const float* m1  = (const float*)d_in[12];
    const float* v1  = (const float*)d_in[13];
    const float* g3  = (const float*)d_in[14];
    const float* b3  = (const float*)d_in[15];
    const float* m3  = (const float*)d_in[16];
    const float* v3  = (const float*)d_in[17];
    const float* g2  = (const float*)d_in[18];
    const float* b2  = (const float*)d_in[19];
    const float* m2  = (const float*)d_in[20];
    const float* v2  = (const float*)d_in[21];

    float* out = (float*)d_out;
    float* ws  = (float*)d_ws;

    float* offs1 = ws;                    // 8*18*3136 floats (reused for offs2)
    float* offs3 = ws + 451584;           // 8*50*3136
    float* mid   = ws + 1705984;          // 8*64*3136
    float* fbase = ws + 3311616;
    _Float16* wT1h = (_Float16*)fbase;                    // 36864 f16
    _Float16* wT3h = (_Float16*)(fbase + 18432);          // 102400 f16
    _Float16* wT2h = (_Float16*)(fbase + 18432 + 51200);  // 36864 f16

    wtrans_k<<<dim3(16, 3), dim3(256), 0, stream>>>(w1, w3, w2, wT1h, wT3h, wT2h);

    offconv_k<6><<<dim3(13 * 3 * 8),  dim3(256), 0, stream>>>(x, ow1, ob1, offs1, 18, 3);
    offconv_k<10><<<dim3(13 * 5 * 8), dim3(256), 0, stream>>>(x, ow3, ob3, offs3, 50, 5);

    dconv_k<1><<<dim3(784), dim3(256), 0, stream>>>(
        x, offs1, offs3, wT1h, wT3h, g1, b1, m1, v1, g3, b3, m3, v3, nullptr, mid);

    offconv_k<6><<<dim3(13 * 3 * 8), dim3(256), 0, stream>>>(mid, ow2, ob2, offs1, 18, 3);

    dconv_k<0><<<dim3(784), dim3(256), 0, stream>>>(
        mid, offs1, nullptr, wT2h, nullptr, g2, b2, m2, v2,
        nullptr, nullptr, nullptr, nullptr, x, out);
}

// Round 9
// 350.208 us; speedup vs baseline: 1.4092x; 1.2474x over previous
//
#include <hip/hip_runtime.h>
#include <math.h>

#define HD 56
#define WD 56
#define CD 64
#define PLANE 3136   // 56*56

typedef _Float16 f16x8 __attribute__((ext_vector_type(8)));
typedef _Float16 f16x2 __attribute__((ext_vector_type(2)));
typedef float    f32x4 __attribute__((ext_vector_type(4)));

// ---- weight transpose + f16: wT[k][o][c] = (f16)w[o][c][k] ----
__global__ __launch_bounds__(256) void wtrans_k(
    const float* __restrict__ w1, const float* __restrict__ w3, const float* __restrict__ w2,
    _Float16* __restrict__ t1, _Float16* __restrict__ t3, _Float16* __restrict__ t2)
{
    const float* src; _Float16* dst; int K2;
    if (blockIdx.y == 0)      { src = w1; dst = t1; K2 = 9;  }
    else if (blockIdx.y == 1) { src = w3; dst = t3; K2 = 25; }
    else                      { src = w2; dst = t2; K2 = 9;  }
    int total = 64 * 64 * K2;
    for (int idx = blockIdx.x * 256 + threadIdx.x; idx < total; idx += gridDim.x * 256) {
        int k = idx >> 12;
        int o = (idx >> 6) & 63;
        int c = idx & 63;
        dst[idx] = (_Float16)src[(o * 64 + c) * K2 + k];
    }
}

// ---- channel transpose to f16: dst[b][pix][c] = (f16)src[b][c][pix] ----
__global__ __launch_bounds__(256) void xt_k(const float* __restrict__ src, _Float16* __restrict__ dst)
{
    int b  = blockIdx.y;
    int px = blockIdx.x * 64 + (threadIdx.x & 63);
    int cg = threadIdx.x >> 6;            // channel group: cg*16 .. +16
    const float* s = src + (size_t)b * CD * PLANE + px;
    f16x8 lo, hi;
#pragma unroll
    for (int i = 0; i < 8; ++i) lo[i] = (_Float16)s[(cg * 16 + i) * PLANE];
#pragma unroll
    for (int i = 0; i < 8; ++i) hi[i] = (_Float16)s[(cg * 16 + 8 + i) * PLANE];
    _Float16* d = dst + ((size_t)b * PLANE + px) * 64 + cg * 16;
    *(f16x8*)d = lo;
    *(f16x8*)(d + 8) = hi;
}

// ---- bilinear tap table: entry = {u16 i00,i01,i10,i11 ; f16 w00,w01,w10,w11} ----
__global__ __launch_bounds__(256) void tapprep_k(
    const float* __restrict__ offsA, const float* __restrict__ offsB,
    uint4* __restrict__ tbl, int NT)
{
    int pix = blockIdx.x * 256 + threadIdx.x;
    if (pix >= PLANE) return;
    int tap = blockIdx.y;
    int b   = blockIdx.z;
    int kk, kw, pad; const float* offs;
    if (NT == 9 || tap < 9) { kk = tap;     offs = offsA + b * (18 * PLANE); kw = 3; pad = 2; }
    else                    { kk = tap - 9; offs = offsB + b * (50 * PLANE); kw = 5; pad = 4; }
    int ho = pix / WD, wo = pix - ho * WD;
    float dy = offs[(2 * kk) * PLANE + pix];
    float dx = offs[(2 * kk + 1) * PLANE + pix];
    float py = dy + (float)((kk / kw) * 2 - pad + ho);
    float px = dx + (float)((kk % kw) * 2 - pad + wo);
    float fy = floorf(py), fx = floorf(px);
    float wy1 = py - fy, wx1 = px - fx;
    float wy0 = 1.f - wy1, wx0 = 1.f - wx1;
    int y0 = (int)fy, x0 = (int)fx;
    int y1 = y0 + 1, x1 = x0 + 1;
    float vy0 = (y0 >= 0 && y0 < HD) ? 1.f : 0.f;
    float vy1 = (y1 >= 0 && y1 < HD) ? 1.f : 0.f;
    float vx0 = (x0 >= 0 && x0 < WD) ? 1.f : 0.f;
    float vx1 = (x1 >= 0 && x1 < WD) ? 1.f : 0.f;
    int cy0 = min(max(y0, 0), HD - 1), cy1 = min(max(y1, 0), HD - 1);
    int cx0 = min(max(x0, 0), WD - 1), cx1 = min(max(x1, 0), WD - 1);
    unsigned i00 = (unsigned)(cy0 * WD + cx0), i01 = (unsigned)(cy0 * WD + cx1);
    unsigned i10 = (unsigned)(cy1 * WD + cx0), i11 = (unsigned)(cy1 * WD + cx1);
    f16x2 wl = {(_Float16)(wy0 * wx0 * vy0 * vx0), (_Float16)(wy0 * wx1 * vy0 * vx1)};
    f16x2 wh = {(_Float16)(wy1 * wx0 * vy1 * vx0), (_Float16)(wy1 * wx1 * vy1 * vx1)};
    uint4 e;
    e.x = i00 | (i01 << 16);
    e.y = i10 | (i11 << 16);
    e.z = __builtin_bit_cast(unsigned int, wl);
    e.w = __builtin_bit_cast(unsigned int, wh);
    tbl[((size_t)(b * NT + tap)) * PLANE + pix] = e;
}

// ---------------- 3x3 offset conv (fp32), pad 1, stride 1 ----------------
template<int COT>
__global__ __launch_bounds__(256) void offconv_k(
    const float* __restrict__ src, const float* __restrict__ w,
    const float* __restrict__ bias, float* __restrict__ dst, int Co, int NG)
{
    __shared__ float wl[COT * 768];
    int tid = threadIdx.x;
    int bid = blockIdx.x;
    int b   = bid & 7;
    int r   = bid >> 3;
    int co0 = (r % NG) * COT;
    int pixblk = r / NG;

    for (int idx = tid; idx < COT * 768; idx += 256) wl[idx] = 0.f;
    __syncthreads();
    for (int idx = tid; idx < COT * 576; idx += 256) {
        int i   = idx / 576;
        int rem = idx - i * 576;
        int c   = rem / 9;
        int kk  = rem - c * 9;
        wl[i * 768 + c * 12 + kk] = w[(co0 + i) * 576 + rem];
    }
    __syncthreads();

    int pix = pixblk * 256 + tid;
    if (pix >= PLANE) return;
    int ho = pix / WD, wo = pix - ho * WD;

    float acc[COT];
#pragma unroll
    for (int i = 0; i < COT; ++i) acc[i] = bias[co0 + i];

    const float* sb = src + b * (CD * PLANE);
    for (int c = 0; c < CD; ++c) {
        const float* sc = sb + c * PLANE;
        float v[12];
#pragma unroll
        for (int ky = 0; ky < 3; ++ky) {
            int y = ho + ky - 1;
            bool yv = (unsigned)y < (unsigned)HD;
#pragma unroll
            for (int kx = 0; kx < 3; ++kx) {
                int xx = wo + kx - 1;
                v[ky * 3 + kx] = (yv && (unsigned)xx < (unsigned)WD) ? sc[y * WD + xx] : 0.f;
            }
        }
        v[9] = v[10] = v[11] = 0.f;
#pragma unroll
        for (int i = 0; i < COT; ++i) {
            const float* wr = &wl[i * 768 + c * 12];
#pragma unroll
            for (int kk = 0; kk < 12; ++kk) acc[i] += wr[kk] * v[kk];
        }
    }
    float* db = dst + (size_t)(b * Co + co0) * PLANE + pix;
#pragma unroll
    for (int i = 0; i < COT; ++i) db[i * PLANE] = acc[i];
}

// ---------------- deformable conv + BN: table-driven, xt-gather, K-split ----------------
// MERGED==1: out = relu(bnA(dcA)) + relu(bnB(dcB));  MERGED==0: out = relu(bnA(dcA)+addsrc)
// grid 784 x 256 = 3136 waves; batch = bid&7. Block = 2 tiles x 2 K-halves.
// Wave (tile, kh): 16 pixels x 64 out-ch over channels [kh*32,+32).
// Per tap: 1 entry load + 4 corner f16x8 loads + 4 A-frag loads + pk-f16 bf + 4 MFMA.
// Pipeline: entry(t+2), corners/af(t+1) issued BEFORE bf(t) -> full-iteration issue-use gap.
template<int MERGED>
__global__ __launch_bounds__(256) void dconv_k(
    const _Float16* __restrict__ xt,      // [b][pix][64] f16
    const uint4* __restrict__ tbl,        // [b][NT][PLANE]
    const _Float16* __restrict__ wTA, const _Float16* __restrict__ wTB, // [k][o][c]
    const float* __restrict__ gA, const float* __restrict__ bA,
    const float* __restrict__ mA, const float* __restrict__ vA,
    const float* __restrict__ gB, const float* __restrict__ bB,
    const float* __restrict__ mB, const float* __restrict__ vB,
    const float* __restrict__ addsrc, float* __restrict__ out)
{
    constexpr int NT = MERGED ? 34 : 9;
    constexpr int RS = MERGED ? 32 : 16;
    __shared__ float red[2][RS * 64];

    int tid = threadIdx.x;
    int bid = blockIdx.x;
    int b   = bid & 7;
    int l   = tid & 63;
    int n   = l & 15;
    int g   = l >> 4;
    int w   = tid >> 6;
    int kh  = w & 1;
    int pr  = w >> 1;
    int tile = (bid >> 3) * 2 + pr;
    int pix = tile * 16 + n;
    int ckoff = kh * 32 + g * 8;

    const _Float16* xp = xt + (size_t)b * PLANE * 64 + ckoff;   // + idx*64
    const uint4*    tp = tbl + (size_t)b * NT * PLANE + pix;    // + tap*PLANE
    int afoff = n * 64 + ckoff;                                  // + tapbase + ot*1024

    f32x4 accA[4], accB[4];
#pragma unroll
    for (int ot = 0; ot < 4; ++ot) {
        accA[ot] = (f32x4){0.f, 0.f, 0.f, 0.f};
        accB[ot] = (f32x4){0.f, 0.f, 0.f, 0.f};
    }

    f16x8 v00, v01, v10, v11, af0, af1, af2, af3;
    _Float16 w0, w1, w2, w3;
    uint4 e_cur;

    // ---- prologue ----
    {
        uint4 e0 = tp[0];                                  // entry(0) (serial wait)
        e_cur = tp[(NT > 1 ? 1 : 0) * PLANE];              // entry(1) issued first
        unsigned i00 = e0.x & 0xffffu, i01 = e0.x >> 16;
        unsigned i10 = e0.y & 0xffffu, i11 = e0.y >> 16;
        v00 = *(const f16x8*)(xp + i00 * 64);              // corners(0)
        v01 = *(const f16x8*)(xp + i01 * 64);
        v10 = *(const f16x8*)(xp + i10 * 64);
        v11 = *(const f16x8*)(xp + i11 * 64);
        const _Float16* wk = wTA;                          // tap 0 is A
        af0 = *(const f16x8*)(wk + afoff);
        af1 = *(const f16x8*)(wk + afoff + 1024);
        af2 = *(const f16x8*)(wk + afoff + 2048);
        af3 = *(const f16x8*)(wk + afoff + 3072);
        f16x2 wl = __builtin_bit_cast(f16x2, e0.z);
        f16x2 wh = __builtin_bit_cast(f16x2, e0.w);
        w0 = wl.x; w1 = wl.y; w2 = wh.x; w3 = wh.y;
    }

#pragma unroll 2
    for (int tap = 0; tap < NT; ++tap) {
        bool hn = (tap + 1 < NT);
        f16x8 nv00, nv01, nv10, nv11, naf0, naf1, naf2, naf3;
        uint4 e_nxt;
        if (hn) {
            int t2 = (tap + 2 < NT) ? (tap + 2) : (NT - 1);
            e_nxt = tp[t2 * PLANE];                        // entry(t+2) FIRST
            unsigned i00 = e_cur.x & 0xffffu, i01 = e_cur.x >> 16;
            unsigned i10 = e_cur.y & 0xffffu, i11 = e_cur.y >> 16;
            nv00 = *(const f16x8*)(xp + i00 * 64);         // corners(t+1)
            nv01 = *(const f16x8*)(xp + i01 * 64);
            nv10 = *(const f16x8*)(xp + i10 * 64);
            nv11 = *(const f16x8*)(xp + i11 * 64);
            const _Float16* wk = (!MERGED || tap + 1 < 9) ? (wTA + (tap + 1) * 4096)
                                                          : (wTB + (tap - 8) * 4096);
            naf0 = *(const f16x8*)(wk + afoff);            // A-frags(t+1)
            naf1 = *(const f16x8*)(wk + afoff + 1024);
            naf2 = *(const f16x8*)(wk + afoff + 2048);
            naf3 = *(const f16x8*)(wk + afoff + 3072);
        }
        // bf(t): packed-f16 bilinear combine (corners issued one full iter ago)
        f16x8 bf = v00 * w0 + v01 * w1 + v10 * w2 + v11 * w3;
        if (!MERGED || tap < 9) {
            accA[0] = __builtin_amdgcn_mfma_f32_16x16x32_f16(af0, bf, accA[0], 0, 0, 0);
            accA[1] = __builtin_amdgcn_mfma_f32_16x16x32_f16(af1, bf, accA[1], 0, 0, 0);
            accA[2] = __builtin_amdgcn_mfma_f32_16x16x32_f16(af2, bf, accA[2], 0, 0, 0);
            accA[3] = __builtin_amdgcn_mfma_f32_16x16x32_f16(af3, bf, accA[3], 0, 0, 0);
        } else {
            accB[0] = __builtin_amdgcn_mfma_f32_16x16x32_f16(af0, bf, accB[0], 0, 0, 0);
            accB[1] = __builtin_amdgcn_mfma_f32_16x16x32_f16(af1, bf, accB[1], 0, 0, 0);
            accB[2] = __builtin_amdgcn_mfma_f32_16x16x32_f16(af2, bf, accB[2], 0, 0, 0);
            accB[3] = __builtin_amdgcn_mfma_f32_16x16x32_f16(af3, bf, accB[3], 0, 0, 0);
        }
        if (hn) {
            v00 = nv00; v01 = nv01; v10 = nv10; v11 = nv11;
            af0 = naf0; af1 = naf1; af2 = naf2; af3 = naf3;
            f16x2 wl = __builtin_bit_cast(f16x2, e_cur.z);
            f16x2 wh = __builtin_bit_cast(f16x2, e_cur.w);
            w0 = wl.x; w1 = wl.y; w2 = wh.x; w3 = wh.y;
            e_cur = e_nxt;
        }
    }

    // K-half reduce: kh=1 writes partials, kh=0 adds + epilogue
    if (kh == 1) {
#pragma unroll
        for (int ot = 0; ot < 4; ++ot)
#pragma unroll
            for (int rr = 0; rr < 4; ++rr) {
                red[pr][(ot * 4 + rr) * 64 + l] = accA[ot][rr];
                if (MERGED) red[pr][(16 + ot * 4 + rr) * 64 + l] = accB[ot][rr];
            }
    }
    __syncthreads();
    if (kh == 0) {
#pragma unroll
        for (int ot = 0; ot < 4; ++ot) {
#pragma unroll
            for (int rr = 0; rr < 4; ++rr) {
                int o = ot * 16 + g * 4 + rr;
                float aA = accA[ot][rr] + red[pr][(ot * 4 + rr) * 64 + l];
                float ivA = gA[o] * (1.f / sqrtf(vA[o] + 1e-5f));
                float shA = bA[o] - mA[o] * ivA;
                size_t oidx = (size_t)(b * 64 + o) * PLANE + pix;
                float vA_ = aA * ivA + shA;
                if (MERGED) {
                    float aB = accB[ot][rr] + red[pr][(16 + ot * 4 + rr) * 64 + l];
                    float ivB = gB[o] * (1.f / sqrtf(vB[o] + 1e-5f));
                    float shB = bB[o] - mB[o] * ivB;
                    float vB_ = aB * ivB + shB;
                    out[oidx] = fmaxf(vA_, 0.f) + fmaxf(vB_, 0.f);
                } else {
                    out[oidx] = fmaxf(vA_ + addsrc[oidx], 0.f);
                }
            }
        }
    }
}

extern "C" void kernel_launch(void* const* d_in, const int* in_sizes, int n_in,
                              void* d_out, int out_size, void* d_ws, size_t ws_size,
                              hipStream_t stream) {
    const float* x   = (const float*)d_in[0];
    const float* ow1 = (const float*)d_in[1];
    const float* ob1 = (const float*)d_in[2];
    const float* ow3 = (const float*)d_in[3];
    const float* ob3 = (const float*)d_in[4];
    const float* ow2 = (const float*)d_in[5];
    const float* ob2 = (const float*)d_in[6];
    const float* w1  = (const float*)d_in[7];
    const float* w3  = (const float*)d_in[8];
    const float* w2  = (const float*)d_in[9];
    const float* g1  = (const float*)d_in[10];
    const float* b1  = (const float*)d_in[11];
    const float* m1  = (const float*)d_in[12];
    const float* v1  = (const float*)d_in[13];
    const float* g3  = (const float*)d_in[14];
    const float* b3  = (const float*)d_in[15];
    const float* m3  = (const float*)d_in[16];
    const float* v3  = (const float*)d_in[17];
    const float* g2  = (const float*)d_in[18];
    const float* b2  = (const float*)d_in[19];
    const float* m2  = (const float*)d_in[20];
    const float* v2  = (const float*)d_in[21];

    float* out = (float*)d_out;
    float* ws  = (float*)d_ws;

    // ws layout (float units)
    float* offs1 = ws;                          // 451584 (reused for offs2)
    float* offs3 = ws + 451584;                 // 1254400 (mt overlays after tapprep13)
    float* mid   = ws + 1705984;                // 1605632
    float* fbase = ws + 3311616;                // weights f16: 88064 floats
    _Float16* wT1h = (_Float16*)fbase;                    // 36864 f16
    _Float16* wT3h = (_Float16*)(fbase + 18432);          // 102400 f16
    _Float16* wT2h = (_Float16*)(fbase + 18432 + 51200);  // 36864 f16
    _Float16* xth  = (_Float16*)(ws + 3399680);           // 1605632 f16 = 802816 fl
    uint4*    tbl  = (uint4*)(ws + 4202496);              // 852992 * 16B = 3411968 fl
    _Float16* mth  = (_Float16*)offs3;                    // overlay (offs3 dead after tapprep13)

    wtrans_k<<<dim3(16, 3), dim3(256), 0, stream>>>(w1, w3, w2, wT1h, wT3h, wT2h);
    xt_k<<<dim3(49, 8), dim3(256), 0, stream>>>(x, xth);

    offconv_k<6><<<dim3(13 * 3 * 8),  dim3(256), 0, stream>>>(x, ow1, ob1, offs1, 18, 3);
    offconv_k<10><<<dim3(13 * 5 * 8), dim3(256), 0, stream>>>(x, ow3, ob3, offs3, 50, 5);

    tapprep_k<<<dim3(13, 34, 8), dim3(256), 0, stream>>>(offs1, offs3, tbl, 34);

    dconv_k<1><<<dim3(784), dim3(256), 0, stream>>>(
        xth, tbl, wT1h, wT3h, g1, b1, m1, v1, g3, b3, m3, v3, nullptr, mid);

    xt_k<<<dim3(49, 8), dim3(256), 0, stream>>>(mid, mth);
    offconv_k<6><<<dim3(13 * 3 * 8), dim3(256), 0, stream>>>(mid, ow2, ob2, offs1, 18, 3);

    tapprep_k<<<dim3(13, 9, 8), dim3(256), 0, stream>>>(offs1, offs1, tbl, 9);

    dconv_k<0><<<dim3(784), dim3(256), 0, stream>>>(
        mth, tbl, wT2h, wT2h, g2, b2, m2, v2, g2, b2, m2, v2, x, out);
}

// Round 10
// 329.931 us; speedup vs baseline: 1.4958x; 1.0615x over previous
//
#include <hip/hip_runtime.h>
#include <math.h>

#define HD 56
#define WD 56
#define CD 64
#define PLANE 3136   // 56*56

typedef _Float16 f16x8 __attribute__((ext_vector_type(8)));
typedef _Float16 f16x4 __attribute__((ext_vector_type(4)));
typedef _Float16 f16x2 __attribute__((ext_vector_type(2)));
typedef float    f32x4 __attribute__((ext_vector_type(4)));

// ---- weight transpose + f16: wT[k][o][c] = (f16)w[o][c][k] ----
__global__ __launch_bounds__(256) void wtrans_k(
    const float* __restrict__ w1, const float* __restrict__ w3, const float* __restrict__ w2,
    _Float16* __restrict__ t1, _Float16* __restrict__ t3, _Float16* __restrict__ t2)
{
    const float* src; _Float16* dst; int K2;
    if (blockIdx.y == 0)      { src = w1; dst = t1; K2 = 9;  }
    else if (blockIdx.y == 1) { src = w3; dst = t3; K2 = 25; }
    else                      { src = w2; dst = t2; K2 = 9;  }
    int total = 64 * 64 * K2;
    for (int idx = blockIdx.x * 256 + threadIdx.x; idx < total; idx += gridDim.x * 256) {
        int k = idx >> 12;
        int o = (idx >> 6) & 63;
        int c = idx & 63;
        dst[idx] = (_Float16)src[(o * 64 + c) * K2 + k];
    }
}

// ---- channel transpose to f16: dst[b][pix][c] = (f16)src[b][c][pix] ----
__global__ __launch_bounds__(256) void xt_k(const float* __restrict__ src, _Float16* __restrict__ dst)
{
    int b  = blockIdx.y;
    int px = blockIdx.x * 64 + (threadIdx.x & 63);
    int cg = threadIdx.x >> 6;            // channel group: cg*16 .. +16
    const float* s = src + (size_t)b * CD * PLANE + px;
    f16x8 lo, hi;
#pragma unroll
    for (int i = 0; i < 8; ++i) lo[i] = (_Float16)s[(cg * 16 + i) * PLANE];
#pragma unroll
    for (int i = 0; i < 8; ++i) hi[i] = (_Float16)s[(cg * 16 + 8 + i) * PLANE];
    _Float16* d = dst + ((size_t)b * PLANE + px) * 64 + cg * 16;
    *(f16x8*)d = lo;
    *(f16x8*)(d + 8) = hi;
}

// ---- bilinear tap table: entry = {u16 i00,i01,i10,i11 ; f16 w00,w01,w10,w11} ----
__global__ __launch_bounds__(256) void tapprep_k(
    const float* __restrict__ offsA, const float* __restrict__ offsB,
    uint4* __restrict__ tbl, int NT)
{
    int pix = blockIdx.x * 256 + threadIdx.x;
    if (pix >= PLANE) return;
    int tap = blockIdx.y;
    int b   = blockIdx.z;
    int kk, kw, pad; const float* offs;
    if (NT == 9 || tap < 9) { kk = tap;     offs = offsA + b * (18 * PLANE); kw = 3; pad = 2; }
    else                    { kk = tap - 9; offs = offsB + b * (50 * PLANE); kw = 5; pad = 4; }
    int ho = pix / WD, wo = pix - ho * WD;
    float dy = offs[(2 * kk) * PLANE + pix];
    float dx = offs[(2 * kk + 1) * PLANE + pix];
    float py = dy + (float)((kk / kw) * 2 - pad + ho);
    float px = dx + (float)((kk % kw) * 2 - pad + wo);
    float fy = floorf(py), fx = floorf(px);
    float wy1 = py - fy, wx1 = px - fx;
    float wy0 = 1.f - wy1, wx0 = 1.f - wx1;
    int y0 = (int)fy, x0 = (int)fx;
    int y1 = y0 + 1, x1 = x0 + 1;
    float vy0 = (y0 >= 0 && y0 < HD) ? 1.f : 0.f;
    float vy1 = (y1 >= 0 && y1 < HD) ? 1.f : 0.f;
    float vx0 = (x0 >= 0 && x0 < WD) ? 1.f : 0.f;
    float vx1 = (x1 >= 0 && x1 < WD) ? 1.f : 0.f;
    int cy0 = min(max(y0, 0), HD - 1), cy1 = min(max(y1, 0), HD - 1);
    int cx0 = min(max(x0, 0), WD - 1), cx1 = min(max(x1, 0), WD - 1);
    unsigned i00 = (unsigned)(cy0 * WD + cx0), i01 = (unsigned)(cy0 * WD + cx1);
    unsigned i10 = (unsigned)(cy1 * WD + cx0), i11 = (unsigned)(cy1 * WD + cx1);
    f16x2 wl = {(_Float16)(wy0 * wx0 * vy0 * vx0), (_Float16)(wy0 * wx1 * vy0 * vx1)};
    f16x2 wh = {(_Float16)(wy1 * wx0 * vy1 * vx0), (_Float16)(wy1 * wx1 * vy1 * vx1)};
    uint4 e;
    e.x = i00 | (i01 << 16);
    e.y = i10 | (i11 << 16);
    e.z = __builtin_bit_cast(unsigned int, wl);
    e.w = __builtin_bit_cast(unsigned int, wh);
    tbl[((size_t)(b * NT + tap)) * PLANE + pix] = e;
}

// ---------------- 3x3 offset conv (fp32), pad 1, stride 1 ----------------
template<int COT>
__global__ __launch_bounds__(256) void offconv_k(
    const float* __restrict__ src, const float* __restrict__ w,
    const float* __restrict__ bias, float* __restrict__ dst, int Co, int NG)
{
    __shared__ float wl[COT * 768];
    int tid = threadIdx.x;
    int bid = blockIdx.x;
    int b   = bid & 7;
    int r   = bid >> 3;
    int co0 = (r % NG) * COT;
    int pixblk = r / NG;

    for (int idx = tid; idx < COT * 768; idx += 256) wl[idx] = 0.f;
    __syncthreads();
    for (int idx = tid; idx < COT * 576; idx += 256) {
        int i   = idx / 576;
        int rem = idx - i * 576;
        int c   = rem / 9;
        int kk  = rem - c * 9;
        wl[i * 768 + c * 12 + kk] = w[(co0 + i) * 576 + rem];
    }
    __syncthreads();

    int pix = pixblk * 256 + tid;
    if (pix >= PLANE) return;
    int ho = pix / WD, wo = pix - ho * WD;

    float acc[COT];
#pragma unroll
    for (int i = 0; i < COT; ++i) acc[i] = bias[co0 + i];

    const float* sb = src + b * (CD * PLANE);
    for (int c = 0; c < CD; ++c) {
        const float* sc = sb + c * PLANE;
        float v[12];
#pragma unroll
        for (int ky = 0; ky < 3; ++ky) {
            int y = ho + ky - 1;
            bool yv = (unsigned)y < (unsigned)HD;
#pragma unroll
            for (int kx = 0; kx < 3; ++kx) {
                int xx = wo + kx - 1;
                v[ky * 3 + kx] = (yv && (unsigned)xx < (unsigned)WD) ? sc[y * WD + xx] : 0.f;
            }
        }
        v[9] = v[10] = v[11] = 0.f;
#pragma unroll
        for (int i = 0; i < COT; ++i) {
            const float* wr = &wl[i * 768 + c * 12];
#pragma unroll
            for (int kk = 0; kk < 12; ++kk) acc[i] += wr[kk] * v[kk];
        }
    }
    float* db = dst + (size_t)(b * Co + co0) * PLANE + pix;
#pragma unroll
    for (int i = 0; i < COT; ++i) db[i * PLANE] = acc[i];
}

// ---------------- deformable conv + BN: table-driven, K-split AND tap-split ----------------
// MERGED==1: out = relu(bnA(dcA)) + relu(bnB(dcB)); also writes outh = (f16)out in [pix][c].
// MERGED==0: out = relu(bnA(dcA) + addsrc)
// grid 1568 = 196 tiles x 8 batch; batch = bid&7 (XCD-local). Block = 1 tile x 4 waves.
// Wave (kh = w&1, tg = w>>1): 16 pixels x 64 out-ch, channels [kh*32,+32),
//   taps [tg*HALF, ...) (17/17 merged, 5/4 not). 4-way partial reduce via LDS at end.
template<int MERGED>
__global__ __launch_bounds__(256) void dconv_k(
    const _Float16* __restrict__ xt,      // [b][pix][64] f16
    const uint4* __restrict__ tbl,        // [b][NT][PLANE]
    const _Float16* __restrict__ wTA, const _Float16* __restrict__ wTB, // [k][o][c]
    const float* __restrict__ gA, const float* __restrict__ bA,
    const float* __restrict__ mA, const float* __restrict__ vA,
    const float* __restrict__ gB, const float* __restrict__ bB,
    const float* __restrict__ mB, const float* __restrict__ vB,
    const float* __restrict__ addsrc, float* __restrict__ out,
    _Float16* __restrict__ outh)
{
    constexpr int NT   = MERGED ? 34 : 9;
    constexpr int HALF = MERGED ? 17 : 5;
    constexpr int RS   = MERGED ? 32 : 16;
    __shared__ float red[3][RS * 64];

    int tid = threadIdx.x;
    int bid = blockIdx.x;
    int b    = bid & 7;
    int tile = bid >> 3;
    int l   = tid & 63;
    int n   = l & 15;
    int g   = l >> 4;
    int w   = tid >> 6;
    int kh  = w & 1;
    int tg  = w >> 1;
    int pix = tile * 16 + n;
    int ckoff = kh * 32 + g * 8;
    int base = tg ? HALF : 0;
    int cnt  = tg ? (NT - HALF) : HALF;

    const _Float16* xp = xt + (size_t)b * PLANE * 64 + ckoff;   // + idx*64
    const uint4*    tp = tbl + (size_t)b * NT * PLANE + pix;    // + tap*PLANE
    int afoff = n * 64 + ckoff;                                  // + tapbase + ot*1024

    f32x4 accA[4], accB[4];
#pragma unroll
    for (int ot = 0; ot < 4; ++ot) {
        accA[ot] = (f32x4){0.f, 0.f, 0.f, 0.f};
        accB[ot] = (f32x4){0.f, 0.f, 0.f, 0.f};
    }

    f16x8 v00, v01, v10, v11, af0, af1, af2, af3;
    _Float16 w0, w1, w2, w3;
    uint4 e_cur;

    // ---- prologue (tap = base) ----
    {
        uint4 e0 = tp[base * PLANE];
        int t1 = (cnt > 1) ? base + 1 : base;
        e_cur = tp[t1 * PLANE];
        unsigned i00 = e0.x & 0xffffu, i01 = e0.x >> 16;
        unsigned i10 = e0.y & 0xffffu, i11 = e0.y >> 16;
        v00 = *(const f16x8*)(xp + i00 * 64);
        v01 = *(const f16x8*)(xp + i01 * 64);
        v10 = *(const f16x8*)(xp + i10 * 64);
        v11 = *(const f16x8*)(xp + i11 * 64);
        const _Float16* wk = (!MERGED || base < 9) ? (wTA + base * 4096) : (wTB + (base - 9) * 4096);
        af0 = *(const f16x8*)(wk + afoff);
        af1 = *(const f16x8*)(wk + afoff + 1024);
        af2 = *(const f16x8*)(wk + afoff + 2048);
        af3 = *(const f16x8*)(wk + afoff + 3072);
        f16x2 wl = __builtin_bit_cast(f16x2, e0.z);
        f16x2 wh = __builtin_bit_cast(f16x2, e0.w);
        w0 = wl.x; w1 = wl.y; w2 = wh.x; w3 = wh.y;
    }

#pragma unroll 2
    for (int j = 0; j < cnt; ++j) {
        int tap = base + j;
        bool hn = (j + 1 < cnt);
        f16x8 nv00, nv01, nv10, nv11, naf0, naf1, naf2, naf3;
        uint4 e_nxt;
        if (hn) {
            int t2 = (j + 2 < cnt) ? (tap + 2) : (base + cnt - 1);
            e_nxt = tp[t2 * PLANE];                        // entry(t+2) FIRST
            unsigned i00 = e_cur.x & 0xffffu, i01 = e_cur.x >> 16;
            unsigned i10 = e_cur.y & 0xffffu, i11 = e_cur.y >> 16;
            nv00 = *(const f16x8*)(xp + i00 * 64);         // corners(t+1)
            nv01 = *(const f16x8*)(xp + i01 * 64);
            nv10 = *(const f16x8*)(xp + i10 * 64);
            nv11 = *(const f16x8*)(xp + i11 * 64);
            const _Float16* wk = (!MERGED || tap + 1 < 9) ? (wTA + (tap + 1) * 4096)
                                                          : (wTB + (tap - 8) * 4096);
            naf0 = *(const f16x8*)(wk + afoff);            // A-frags(t+1)
            naf1 = *(const f16x8*)(wk + afoff + 1024);
            naf2 = *(const f16x8*)(wk + afoff + 2048);
            naf3 = *(const f16x8*)(wk + afoff + 3072);
        }
        f16x8 bf = v00 * w0 + v01 * w1 + v10 * w2 + v11 * w3;
        if (!MERGED || tap < 9) {
            accA[0] = __builtin_amdgcn_mfma_f32_16x16x32_f16(af0, bf, accA[0], 0, 0, 0);
            accA[1] = __builtin_amdgcn_mfma_f32_16x16x32_f16(af1, bf, accA[1], 0, 0, 0);
            accA[2] = __builtin_amdgcn_mfma_f32_16x16x32_f16(af2, bf, accA[2], 0, 0, 0);
            accA[3] = __builtin_amdgcn_mfma_f32_16x16x32_f16(af3, bf, accA[3], 0, 0, 0);
        } else {
            accB[0] = __builtin_amdgcn_mfma_f32_16x16x32_f16(af0, bf, accB[0], 0, 0, 0);
            accB[1] = __builtin_amdgcn_mfma_f32_16x16x32_f16(af1, bf, accB[1], 0, 0, 0);
            accB[2] = __builtin_amdgcn_mfma_f32_16x16x32_f16(af2, bf, accB[2], 0, 0, 0);
            accB[3] = __builtin_amdgcn_mfma_f32_16x16x32_f16(af3, bf, accB[3], 0, 0, 0);
        }
        if (hn) {
            v00 = nv00; v01 = nv01; v10 = nv10; v11 = nv11;
            af0 = naf0; af1 = naf1; af2 = naf2; af3 = naf3;
            f16x2 wl = __builtin_bit_cast(f16x2, e_cur.z);
            f16x2 wh = __builtin_bit_cast(f16x2, e_cur.w);
            w0 = wl.x; w1 = wl.y; w2 = wh.x; w3 = wh.y;
            e_cur = e_nxt;
        }
    }

    // 4-way reduce: waves 1..3 write partials, wave 0 sums + epilogue
    if (w > 0) {
#pragma unroll
        for (int ot = 0; ot < 4; ++ot)
#pragma unroll
            for (int rr = 0; rr < 4; ++rr) {
                red[w - 1][(ot * 4 + rr) * 64 + l] = accA[ot][rr];
                if (MERGED) red[w - 1][(16 + ot * 4 + rr) * 64 + l] = accB[ot][rr];
            }
    }
    __syncthreads();
    if (w == 0) {
#pragma unroll
        for (int ot = 0; ot < 4; ++ot) {
            float r0, r1, r2, r3;
#pragma unroll
            for (int rr = 0; rr < 4; ++rr) {
                int ia = (ot * 4 + rr) * 64 + l;
                float aA = accA[ot][rr] + red[0][ia] + red[1][ia] + red[2][ia];
                int o = ot * 16 + g * 4 + rr;
                float ivA = gA[o] * (1.f / sqrtf(vA[o] + 1e-5f));
                float shA = bA[o] - mA[o] * ivA;
                size_t oidx = (size_t)(b * 64 + o) * PLANE + pix;
                float vA_ = aA * ivA + shA;
                float res;
                if (MERGED) {
                    int ib = (16 + ot * 4 + rr) * 64 + l;
                    float aB = accB[ot][rr] + red[0][ib] + red[1][ib] + red[2][ib];
                    float ivB = gB[o] * (1.f / sqrtf(vB[o] + 1e-5f));
                    float shB = bB[o] - mB[o] * ivB;
                    float vB_ = aB * ivB + shB;
                    res = fmaxf(vA_, 0.f) + fmaxf(vB_, 0.f);
                } else {
                    res = fmaxf(vA_ + addsrc[oidx], 0.f);
                }
                out[oidx] = res;
                if (rr == 0) r0 = res; else if (rr == 1) r1 = res;
                else if (rr == 2) r2 = res; else r3 = res;
            }
            if (MERGED) {
                f16x4 hv = {(_Float16)r0, (_Float16)r1, (_Float16)r2, (_Float16)r3};
                *(f16x4*)(outh + ((size_t)b * PLANE + pix) * 64 + ot * 16 + g * 4) = hv;
            }
        }
    }
}

extern "C" void kernel_launch(void* const* d_in, const int* in_sizes, int n_in,
                              void* d_out, int out_size, void* d_ws, size_t ws_size,
                              hipStream_t stream) {
    const float* x   = (const float*)d_in[0];
    const float* ow1 = (const float*)d_in[1];
    const float* ob1 = (const float*)d_in[2];
    const float* ow3 = (const float*)d_in[3];
    const float* ob3 = (const float*)d_in[4];
    const float* ow2 = (const float*)d_in[5];
    const float* ob2 = (const float*)d_in[6];
    const float* w1  = (const float*)d_in[7];
    const float* w3  = (const float*)d_in[8];
    const float* w2  = (const float*)d_in[9];
    const float* g1  = (const float*)d_in[10];
    const float* b1  = (const float*)d_in[11];
    const float* m1  = (const float*)d_in[12];
    const float* v1  = (const float*)d_in[13];
    const float* g3  = (const float*)d_in[14];
    const float* b3  = (const float*)d_in[15];
    const float* m3  = (const float*)d_in[16];
    const float* v3  = (const float*)d_in[17];
    const float* g2  = (const float*)d_in[18];
    const float* b2  = (const float*)d_in[19];
    const float* m2  = (const float*)d_in[20];
    const float* v2  = (const float*)d_in[21];

    float* out = (float*)d_out;
    float* ws  = (float*)d_ws;

    // ws layout (float units)
    float* offs1 = ws;                          // 451584 (reused for offs2)
    float* offs3 = ws + 451584;                 // 1254400 (mth overlays after tapprep34)
    float* mid   = ws + 1705984;                // 1605632
    float* fbase = ws + 3311616;                // weights f16: 88064 floats
    _Float16* wT1h = (_Float16*)fbase;                    // 36864 f16
    _Float16* wT3h = (_Float16*)(fbase + 18432);          // 102400 f16
    _Float16* wT2h = (_Float16*)(fbase + 18432 + 51200);  // 36864 f16
    _Float16* xth  = (_Float16*)(ws + 3399680);           // 1605632 f16 = 802816 fl
    uint4*    tbl  = (uint4*)(ws + 4202496);              // 852992 * 16B
    _Float16* mth  = (_Float16*)offs3;                    // overlay (offs3 dead after tapprep34)

    wtrans_k<<<dim3(16, 3), dim3(256), 0, stream>>>(w1, w3, w2, wT1h, wT3h, wT2h);
    xt_k<<<dim3(49, 8), dim3(256), 0, stream>>>(x, xth);

    offconv_k<6><<<dim3(13 * 3 * 8),  dim3(256), 0, stream>>>(x, ow1, ob1, offs1, 18, 3);
    offconv_k<10><<<dim3(13 * 5 * 8), dim3(256), 0, stream>>>(x, ow3, ob3, offs3, 50, 5);

    tapprep_k<<<dim3(13, 34, 8), dim3(256), 0, stream>>>(offs1, offs3, tbl, 34);

    dconv_k<1><<<dim3(1568), dim3(256), 0, stream>>>(
        xth, tbl, wT1h, wT3h, g1, b1, m1, v1, g3, b3, m3, v3, nullptr, mid, mth);

    offconv_k<6><<<dim3(13 * 3 * 8), dim3(256), 0, stream>>>(mid, ow2, ob2, offs1, 18, 3);

    tapprep_k<<<dim3(13, 9, 8), dim3(256), 0, stream>>>(offs1, offs1, tbl, 9);

    dconv_k<0><<<dim3(1568), dim3(256), 0, stream>>>(
        mth, tbl, wT2h, wT2h, g2, b2, m2, v2, g2, b2, m2, v2, x, out, nullptr);
}

// Round 11
// 200.666 us; speedup vs baseline: 2.4594x; 1.6442x over previous
//
#include <hip/hip_runtime.h>
#include <math.h>

#define HD 56
#define WD 56
#define CD 64
#define PLANE 3136   // 56*56

typedef _Float16 f16x8 __attribute__((ext_vector_type(8)));
typedef _Float16 f16x4 __attribute__((ext_vector_type(4)));
typedef _Float16 f16x2 __attribute__((ext_vector_type(2)));
typedef float    f32x4 __attribute__((ext_vector_type(4)));

// ---- weight transpose + f16 (6 jobs):
//  y=0..2: dconv weights wT[k][o][c] = (f16)w[o][c][k]
//  y=3: ow1 -> owF rows 0..31 (18 valid);  y=4: ow3 -> owF rows 32..95 (50 valid)
//  y=5: ow2 -> owT2 rows 0..31 (18 valid)
__global__ __launch_bounds__(256) void wtrans_k(
    const float* __restrict__ w1, const float* __restrict__ w3, const float* __restrict__ w2,
    const float* __restrict__ ow1, const float* __restrict__ ow3, const float* __restrict__ ow2,
    _Float16* __restrict__ t1, _Float16* __restrict__ t3, _Float16* __restrict__ t2,
    _Float16* __restrict__ owF, _Float16* __restrict__ owT2)
{
    int y = blockIdx.y;
    if (y == 0 || y == 1 || y == 2) {
        const float* src = (y == 0) ? w1 : (y == 1) ? w3 : w2;
        _Float16* dst    = (y == 0) ? t1 : (y == 1) ? t3 : t2;
        int K2 = (y == 1) ? 25 : 9;
        int total = 64 * 64 * K2;
        for (int idx = blockIdx.x * 256 + threadIdx.x; idx < total; idx += gridDim.x * 256) {
            int k = idx >> 12;
            int o = (idx >> 6) & 63;
            int c = idx & 63;
            dst[idx] = (_Float16)src[(o * 64 + c) * K2 + k];
        }
    } else if (y == 3) {
        int total = 9 * 32 * 64;
        for (int idx = blockIdx.x * 256 + threadIdx.x; idx < total; idx += gridDim.x * 256) {
            int k = idx >> 11;
            int o = (idx >> 6) & 31;
            int c = idx & 63;
            owF[k * 6144 + o * 64 + c] = (o < 18) ? (_Float16)ow1[(o * 64 + c) * 9 + k] : (_Float16)0.f;
        }
    } else if (y == 4) {
        int total = 9 * 64 * 64;
        for (int idx = blockIdx.x * 256 + threadIdx.x; idx < total; idx += gridDim.x * 256) {
            int k = idx >> 12;
            int o = (idx >> 6) & 63;
            int c = idx & 63;
            owF[k * 6144 + (32 + o) * 64 + c] = (o < 50) ? (_Float16)ow3[(o * 64 + c) * 9 + k] : (_Float16)0.f;
        }
    } else {
        int total = 9 * 32 * 64;
        for (int idx = blockIdx.x * 256 + threadIdx.x; idx < total; idx += gridDim.x * 256) {
            int k = idx >> 11;
            int o = (idx >> 6) & 31;
            int c = idx & 63;
            owT2[k * 2048 + o * 64 + c] = (o < 18) ? (_Float16)ow2[(o * 64 + c) * 9 + k] : (_Float16)0.f;
        }
    }
}

// ---- channel transpose to f16: dst[b][pix][c] = (f16)src[b][c][pix] ----
__global__ __launch_bounds__(256) void xt_k(const float* __restrict__ src, _Float16* __restrict__ dst)
{
    int b  = blockIdx.y;
    int px = blockIdx.x * 64 + (threadIdx.x & 63);
    int cg = threadIdx.x >> 6;
    const float* s = src + (size_t)b * CD * PLANE + px;
    f16x8 lo, hi;
#pragma unroll
    for (int i = 0; i < 8; ++i) lo[i] = (_Float16)s[(cg * 16 + i) * PLANE];
#pragma unroll
    for (int i = 0; i < 8; ++i) hi[i] = (_Float16)s[(cg * 16 + 8 + i) * PLANE];
    _Float16* d = dst + ((size_t)b * PLANE + px) * 64 + cg * 16;
    *(f16x8*)d = lo;
    *(f16x8*)(d + 8) = hi;
}

// ---------------- offset conv (f16 MFMA) fused with tapprep ----------------
// FUSED==1: src=xt; weights owF [9][96][64] (rows 0..17=conv1/dcA, 32..81=conv3/dcB);
//           emits full 34-tap table (A taps 0..8 use 3x3 d2 p2; B taps 9..33 use 5x5 d2 p4).
// FUSED==0: src=mth; weights owT2 [9][32][64] (18 valid); emits 9-tap table (3x3 d2 p2).
// grid 1568 = 196 tiles x 8 batch (batch = bid&7); block 256 = 4 waves (kh x tapgroup).
// Wave: 16 px x all o-tiles, channels [kh*32,+32), conv taps {0..4} or {5..8}.
// Epilogue: 4-way LDS reduce; each lane holds (dy,dx) pairs -> builds uint4 tbl entries.
template<int FUSED>
__global__ __launch_bounds__(256) void offc_k(
    const _Float16* __restrict__ src,     // [b][pix][64]
    const _Float16* __restrict__ ow,      // [9][OP][64]
    const float* __restrict__ biasA, const float* __restrict__ biasB,
    uint4* __restrict__ tbl)
{
    constexpr int NTILES = FUSED ? 6 : 2;
    constexpr int OP     = FUSED ? 96 : 32;
    constexpr int NTT    = FUSED ? 34 : 9;
    __shared__ float red[4][NTILES * 4 * 64];

    int tid = threadIdx.x;
    int bid = blockIdx.x;
    int b    = bid & 7;
    int tile = bid >> 3;
    int l = tid & 63;
    int n = l & 15;
    int g = l >> 4;
    int w = tid >> 6;
    int kh = w & 1;
    int tg = w >> 1;
    int pix = tile * 16 + n;
    int ho = pix / WD, wo = pix - ho * WD;
    int ckoff = kh * 32 + g * 8;
    const _Float16* sp = src + ((size_t)b * PLANE + pix) * 64 + ckoff;

    f32x4 acc[NTILES];
#pragma unroll
    for (int t = 0; t < NTILES; ++t) acc[t] = (f32x4){0.f, 0.f, 0.f, 0.f};

#define OFFC_TAP(K)                                                            \
    {                                                                          \
        int ky = (K) / 3 - 1, kx = (K) % 3 - 1;                                \
        int yn = ho + ky, xn = wo + kx;                                        \
        f16x8 bf = {(_Float16)0, (_Float16)0, (_Float16)0, (_Float16)0,        \
                    (_Float16)0, (_Float16)0, (_Float16)0, (_Float16)0};       \
        if ((unsigned)yn < (unsigned)HD && (unsigned)xn < (unsigned)WD)        \
            bf = *(const f16x8*)(sp + (ky * WD + kx) * 64);                    \
        const _Float16* wk = ow + (K) * (OP * 64);                             \
        _Pragma("unroll")                                                      \
        for (int t = 0; t < NTILES; ++t) {                                     \
            f16x8 af = *(const f16x8*)(wk + (t * 16 + n) * 64 + ckoff);        \
            acc[t] = __builtin_amdgcn_mfma_f32_16x16x32_f16(af, bf, acc[t], 0, 0, 0); \
        }                                                                      \
    }

    if (tg == 0) {
#pragma unroll
        for (int k = 0; k < 5; ++k) OFFC_TAP(k)
    } else {
#pragma unroll
        for (int k = 5; k < 9; ++k) OFFC_TAP(k)
    }
#undef OFFC_TAP

    // all waves write partials, then wave w handles tiles {w, w+4}
#pragma unroll
    for (int t = 0; t < NTILES; ++t)
#pragma unroll
        for (int rr = 0; rr < 4; ++rr)
            red[w][(t * 4 + rr) * 64 + l] = acc[t][rr];
    __syncthreads();

#pragma unroll
    for (int tt = 0; tt < (NTILES + 3) / 4; ++tt) {
        int t = w + tt * 4;
        if (t < NTILES) {
            float v[4];
#pragma unroll
            for (int rr = 0; rr < 4; ++rr) {
                int ia = (t * 4 + rr) * 64 + l;
                v[rr] = red[0][ia] + red[1][ia] + red[2][ia] + red[3][ia];
            }
            int obase = t * 16 + g * 4;
            bool isB = FUSED && (t >= 2);
            int oc0 = isB ? (obase - 32) : obase;
            const float* bp = isB ? biasB : biasA;
#pragma unroll
            for (int pp = 0; pp < 2; ++pp) {
                int oce = oc0 + pp * 2;
                int kl  = oce >> 1;
                int kmax = isB ? 25 : 9;
                if (kl < kmax) {
                    float dy = v[pp * 2]     + bp[oce];
                    float dx = v[pp * 2 + 1] + bp[oce + 1];
                    int by, bx;
                    if (isB) { int q = kl / 5; by = q * 2 - 4; bx = (kl - q * 5) * 2 - 4; }
                    else     { int q = kl / 3; by = q * 2 - 2; bx = (kl - q * 3) * 2 - 2; }
                    float py = dy + (float)(by + ho);
                    float px = dx + (float)(bx + wo);
                    float fy = floorf(py), fx = floorf(px);
                    float wy1 = py - fy, wx1 = px - fx;
                    float wy0 = 1.f - wy1, wx0 = 1.f - wx1;
                    int y0 = (int)fy, x0 = (int)fx;
                    int y1 = y0 + 1, x1 = x0 + 1;
                    float vy0 = (y0 >= 0 && y0 < HD) ? 1.f : 0.f;
                    float vy1 = (y1 >= 0 && y1 < HD) ? 1.f : 0.f;
                    float vx0 = (x0 >= 0 && x0 < WD) ? 1.f : 0.f;
                    float vx1 = (x1 >= 0 && x1 < WD) ? 1.f : 0.f;
                    int cy0 = min(max(y0, 0), HD - 1), cy1 = min(max(y1, 0), HD - 1);
                    int cx0 = min(max(x0, 0), WD - 1), cx1 = min(max(x1, 0), WD - 1);
                    unsigned i00 = (unsigned)(cy0 * WD + cx0), i01 = (unsigned)(cy0 * WD + cx1);
                    unsigned i10 = (unsigned)(cy1 * WD + cx0), i11 = (unsigned)(cy1 * WD + cx1);
                    f16x2 wl = {(_Float16)(wy0 * wx0 * vy0 * vx0), (_Float16)(wy0 * wx1 * vy0 * vx1)};
                    f16x2 wh = {(_Float16)(wy1 * wx0 * vy1 * vx0), (_Float16)(wy1 * wx1 * vy1 * vx1)};
                    uint4 e;
                    e.x = i00 | (i01 << 16);
                    e.y = i10 | (i11 << 16);
                    e.z = __builtin_bit_cast(unsigned int, wl);
                    e.w = __builtin_bit_cast(unsigned int, wh);
                    int gtap = isB ? (9 + kl) : kl;
                    tbl[((size_t)(b * NTT + gtap)) * PLANE + pix] = e;
                }
            }
        }
    }
}

// ---------------- deformable conv + BN: table-driven, K-split AND tap-split ----------------
// MERGED==1: outh = (f16)(relu(bnA(dcA)) + relu(bnB(dcB))) in [pix][c] layout (f16 only).
// MERGED==0: out  = relu(bnA(dcA) + addsrc)  (fp32 NCHW)
template<int MERGED>
__global__ __launch_bounds__(256) void dconv_k(
    const _Float16* __restrict__ xt,      // [b][pix][64] f16
    const uint4* __restrict__ tbl,        // [b][NT][PLANE]
    const _Float16* __restrict__ wTA, const _Float16* __restrict__ wTB, // [k][o][c]
    const float* __restrict__ gA, const float* __restrict__ bA,
    const float* __restrict__ mA, const float* __restrict__ vA,
    const float* __restrict__ gB, const float* __restrict__ bB,
    const float* __restrict__ mB, const float* __restrict__ vB,
    const float* __restrict__ addsrc, float* __restrict__ out,
    _Float16* __restrict__ outh)
{
    constexpr int NT   = MERGED ? 34 : 9;
    constexpr int HALF = MERGED ? 17 : 5;
    constexpr int RS   = MERGED ? 32 : 16;
    __shared__ float red[3][RS * 64];

    int tid = threadIdx.x;
    int bid = blockIdx.x;
    int b    = bid & 7;
    int tile = bid >> 3;
    int l   = tid & 63;
    int n   = l & 15;
    int g   = l >> 4;
    int w   = tid >> 6;
    int kh  = w & 1;
    int tg  = w >> 1;
    int pix = tile * 16 + n;
    int ckoff = kh * 32 + g * 8;
    int base = tg ? HALF : 0;
    int cnt  = tg ? (NT - HALF) : HALF;

    const _Float16* xp = xt + (size_t)b * PLANE * 64 + ckoff;
    const uint4*    tp = tbl + (size_t)b * NT * PLANE + pix;
    int afoff = n * 64 + ckoff;

    f32x4 accA[4], accB[4];
#pragma unroll
    for (int ot = 0; ot < 4; ++ot) {
        accA[ot] = (f32x4){0.f, 0.f, 0.f, 0.f};
        accB[ot] = (f32x4){0.f, 0.f, 0.f, 0.f};
    }

    f16x8 v00, v01, v10, v11, af0, af1, af2, af3;
    _Float16 w0, w1, w2, w3;
    uint4 e_cur;

    // ---- prologue (tap = base) ----
    {
        uint4 e0 = tp[base * PLANE];
        int t1 = (cnt > 1) ? base + 1 : base;
        e_cur = tp[t1 * PLANE];
        unsigned i00 = e0.x & 0xffffu, i01 = e0.x >> 16;
        unsigned i10 = e0.y & 0xffffu, i11 = e0.y >> 16;
        v00 = *(const f16x8*)(xp + i00 * 64);
        v01 = *(const f16x8*)(xp + i01 * 64);
        v10 = *(const f16x8*)(xp + i10 * 64);
        v11 = *(const f16x8*)(xp + i11 * 64);
        const _Float16* wk = (!MERGED || base < 9) ? (wTA + base * 4096) : (wTB + (base - 9) * 4096);
        af0 = *(const f16x8*)(wk + afoff);
        af1 = *(const f16x8*)(wk + afoff + 1024);
        af2 = *(const f16x8*)(wk + afoff + 2048);
        af3 = *(const f16x8*)(wk + afoff + 3072);
        f16x2 wl = __builtin_bit_cast(f16x2, e0.z);
        f16x2 wh = __builtin_bit_cast(f16x2, e0.w);
        w0 = wl.x; w1 = wl.y; w2 = wh.x; w3 = wh.y;
    }

#pragma unroll 2
    for (int j = 0; j < cnt; ++j) {
        int tap = base + j;
        bool hn = (j + 1 < cnt);
        f16x8 nv00, nv01, nv10, nv11, naf0, naf1, naf2, naf3;
        uint4 e_nxt;
        if (hn) {
            int t2 = (j + 2 < cnt) ? (tap + 2) : (base + cnt - 1);
            e_nxt = tp[t2 * PLANE];                        // entry(t+2) FIRST
            unsigned i00 = e_cur.x & 0xffffu, i01 = e_cur.x >> 16;
            unsigned i10 = e_cur.y & 0xffffu, i11 = e_cur.y >> 16;
            nv00 = *(const f16x8*)(xp + i00 * 64);         // corners(t+1)
            nv01 = *(const f16x8*)(xp + i01 * 64);
            nv10 = *(const f16x8*)(xp + i10 * 64);
            nv11 = *(const f16x8*)(xp + i11 * 64);
            const _Float16* wk = (!MERGED || tap + 1 < 9) ? (wTA + (tap + 1) * 4096)
                                                          : (wTB + (tap - 8) * 4096);
            naf0 = *(const f16x8*)(wk + afoff);            // A-frags(t+1)
            naf1 = *(const f16x8*)(wk + afoff + 1024);
            naf2 = *(const f16x8*)(wk + afoff + 2048);
            naf3 = *(const f16x8*)(wk + afoff + 3072);
        }
        f16x8 bf = v00 * w0 + v01 * w1 + v10 * w2 + v11 * w3;
        if (!MERGED || tap < 9) {
            accA[0] = __builtin_amdgcn_mfma_f32_16x16x32_f16(af0, bf, accA[0], 0, 0, 0);
            accA[1] = __builtin_amdgcn_mfma_f32_16x16x32_f16(af1, bf, accA[1], 0, 0, 0);
            accA[2] = __builtin_amdgcn_mfma_f32_16x16x32_f16(af2, bf, accA[2], 0, 0, 0);
            accA[3] = __builtin_amdgcn_mfma_f32_16x16x32_f16(af3, bf, accA[3], 0, 0, 0);
        } else {
            accB[0] = __builtin_amdgcn_mfma_f32_16x16x32_f16(af0, bf, accB[0], 0, 0, 0);
            accB[1] = __builtin_amdgcn_mfma_f32_16x16x32_f16(af1, bf, accB[1], 0, 0, 0);
            accB[2] = __builtin_amdgcn_mfma_f32_16x16x32_f16(af2, bf, accB[2], 0, 0, 0);
            accB[3] = __builtin_amdgcn_mfma_f32_16x16x32_f16(af3, bf, accB[3], 0, 0, 0);
        }
        if (hn) {
            v00 = nv00; v01 = nv01; v10 = nv10; v11 = nv11;
            af0 = naf0; af1 = naf1; af2 = naf2; af3 = naf3;
            f16x2 wl = __builtin_bit_cast(f16x2, e_cur.z);
            f16x2 wh = __builtin_bit_cast(f16x2, e_cur.w);
            w0 = wl.x; w1 = wl.y; w2 = wh.x; w3 = wh.y;
            e_cur = e_nxt;
        }
    }

    // 4-way reduce: waves 1..3 write partials, wave 0 sums + epilogue
    if (w > 0) {
#pragma unroll
        for (int ot = 0; ot < 4; ++ot)
#pragma unroll
            for (int rr = 0; rr < 4; ++rr) {
                red[w - 1][(ot * 4 + rr) * 64 + l] = accA[ot][rr];
                if (MERGED) red[w - 1][(16 + ot * 4 + rr) * 64 + l] = accB[ot][rr];
            }
    }
    __syncthreads();
    if (w == 0) {
#pragma unroll
        for (int ot = 0; ot < 4; ++ot) {
            float r[4];
#pragma unroll
            for (int rr = 0; rr < 4; ++rr) {
                int ia = (ot * 4 + rr) * 64 + l;
                float aA = accA[ot][rr] + red[0][ia] + red[1][ia] + red[2][ia];
                int o = ot * 16 + g * 4 + rr;
                float ivA = gA[o] * (1.f / sqrtf(vA[o] + 1e-5f));
                float shA = bA[o] - mA[o] * ivA;
                float vA_ = aA * ivA + shA;
                if (MERGED) {
                    int ib = (16 + ot * 4 + rr) * 64 + l;
                    float aB = accB[ot][rr] + red[0][ib] + red[1][ib] + red[2][ib];
                    float ivB = gB[o] * (1.f / sqrtf(vB[o] + 1e-5f));
                    float shB = bB[o] - mB[o] * ivB;
                    float vB_ = aB * ivB + shB;
                    r[rr] = fmaxf(vA_, 0.f) + fmaxf(vB_, 0.f);
                } else {
                    size_t oidx = (size_t)(b * 64 + o) * PLANE + pix;
                    out[oidx] = fmaxf(vA_ + addsrc[oidx], 0.f);
                }
            }
            if (MERGED) {
                f16x4 hv = {(_Float16)r[0], (_Float16)r[1], (_Float16)r[2], (_Float16)r[3]};
                *(f16x4*)(outh + ((size_t)b * PLANE + pix) * 64 + ot * 16 + g * 4) = hv;
            }
        }
    }
}

extern "C" void kernel_launch(void* const* d_in, const int* in_sizes, int n_in,
                              void* d_out, int out_size, void* d_ws, size_t ws_size,
                              hipStream_t stream) {
    const float* x   = (const float*)d_in[0];
    const float* ow1 = (const float*)d_in[1];
    const float* ob1 = (const float*)d_in[2];
    const float* ow3 = (const float*)d_in[3];
    const float* ob3 = (const float*)d_in[4];
    const float* ow2 = (const float*)d_in[5];
    const float* ob2 = (const float*)d_in[6];
    const float* w1  = (const float*)d_in[7];
    const float* w3  = (const float*)d_in[8];
    const float* w2  = (const float*)d_in[9];
    const float* g1  = (const float*)d_in[10];
    const float* b1  = (const float*)d_in[11];
    const float* m1  = (const float*)d_in[12];
    const float* v1  = (const float*)d_in[13];
    const float* g3  = (const float*)d_in[14];
    const float* b3  = (const float*)d_in[15];
    const float* m3  = (const float*)d_in[16];
    const float* v3  = (const float*)d_in[17];
    const float* g2  = (const float*)d_in[18];
    const float* b2  = (const float*)d_in[19];
    const float* m2  = (const float*)d_in[20];
    const float* v2  = (const float*)d_in[21];

    float* out = (float*)d_out;
    float* ws  = (float*)d_ws;

    // ws layout (float units)
    _Float16* xth  = (_Float16*)ws;                 // 1,605,632 f16 = 802,816 fl
    _Float16* mth  = (_Float16*)(ws + 802816);      // 1,605,632 f16
    uint4*    tbl  = (uint4*)(ws + 1605632);        // 852,992 x 16B (34-tap; 9-tap reuses prefix)
    _Float16* wT1h = (_Float16*)(ws + 5017600);     // 36,864 f16
    _Float16* wT3h = wT1h + 36864;                  // 102,400 f16
    _Float16* wT2h = wT3h + 102400;                 // 36,864 f16
    _Float16* owFh = wT2h + 36864;                  // 9*96*64 = 55,296 f16
    _Float16* owT2h= owFh + 55296;                  // 9*32*64 = 18,432 f16

    wtrans_k<<<dim3(16, 6), dim3(256), 0, stream>>>(
        w1, w3, w2, ow1, ow3, ow2, wT1h, wT3h, wT2h, owFh, owT2h);
    xt_k<<<dim3(49, 8), dim3(256), 0, stream>>>(x, xth);

    offc_k<1><<<dim3(1568), dim3(256), 0, stream>>>(xth, owFh, ob1, ob3, tbl);

    dconv_k<1><<<dim3(1568), dim3(256), 0, stream>>>(
        xth, tbl, wT1h, wT3h, g1, b1, m1, v1, g3, b3, m3, v3, nullptr, nullptr, mth);

    offc_k<0><<<dim3(1568), dim3(256), 0, stream>>>(mth, owT2h, ob2, ob2, tbl);

    dconv_k<0><<<dim3(1568), dim3(256), 0, stream>>>(
        mth, tbl, wT2h, wT2h, g2, b2, m2, v2, g2, b2, m2, v2, x, out, nullptr);
}